// Round 9
// baseline (1648.269 us; speedup 1.0000x reference)
//
#include <hip/hip_runtime.h>
#include <stdint.h>
#include <math.h>

// RNN predictor: B=2048, T=1024 teacher-forced + FUT=64 autoregressive, H=128.
// Round-9: weights homed in AGPRs and consumed IN PLACE by inline-asm MFMA
// ("a" constraints on the B operands; every use is "a" so regalloc assigns
// the 128 weight regs to AGPR and writes them once at init). R8 proved the
// hazard discipline (s_nop 2 at chain head, tied s_nop fence after) makes
// inline-asm MFMA safe; R6's NaN was the missing nops, not the "a" path.
//  - 32 MFMA/step in 4 chains (W1/W2 x 2 tiles); Wo MFMA chain DELETED:
//    o = W_out.h via VALU partials + DPP shfl_xor tree (no LDS for the
//    in-wave reduce) + 16-float opart buffer riding the step barrier;
//    o_{i-1} finished at step i start = exactly when AR feedback needs it.
//  - SPB=4, 512 blocks -> 2 blocks/CU, 2 waves/SIMD (unified ~240 <= 256).
//  - packed (hi|lo) u32 h state, one barrier/step, 64-entry output ring.

#define TLEN  1024
#define FUT   64
#define HID   128
#define SPB   4
#define NT    256
#define NSTEP (TLEN + FUT)

typedef float f32x4 __attribute__((ext_vector_type(4)));
typedef uint32_t u32x4 __attribute__((ext_vector_type(4)));

__device__ __forceinline__ float fast_tanh(float v) {
    return 1.0f - 2.0f / (__expf(2.0f * v) + 1.0f);   // saturates correctly
}
__device__ __forceinline__ unsigned short bf16_rn(float f) {
    uint32_t u = __builtin_bit_cast(uint32_t, f);
    uint32_t r = (u + 0x7fffu + ((u >> 16) & 1u)) >> 16;  // RNE
    return (unsigned short)r;
}
__device__ __forceinline__ float bf16f(unsigned short h) {
    uint32_t u = (uint32_t)h << 16;
    return __builtin_bit_cast(float, u);
}

// 8 chained MFMAs on one accumulator; A in arch VGPRs, W read from AGPR
// in place (no copies). s_nop 2 covers the VALU-acc-init -> MFMA SrcC hazard.
#define MFMA_CHAIN8(acc, A, W)                                          \
    asm volatile(                                                       \
        "s_nop 2\n\t"                                                   \
        "v_mfma_f32_16x16x32_bf16 %0, %1, %9, %0\n\t"                   \
        "v_mfma_f32_16x16x32_bf16 %0, %2, %10, %0\n\t"                  \
        "v_mfma_f32_16x16x32_bf16 %0, %3, %11, %0\n\t"                  \
        "v_mfma_f32_16x16x32_bf16 %0, %4, %12, %0\n\t"                  \
        "v_mfma_f32_16x16x32_bf16 %0, %5, %13, %0\n\t"                  \
        "v_mfma_f32_16x16x32_bf16 %0, %6, %14, %0\n\t"                  \
        "v_mfma_f32_16x16x32_bf16 %0, %7, %15, %0\n\t"                  \
        "v_mfma_f32_16x16x32_bf16 %0, %8, %16, %0"                      \
        : "+v"(acc)                                                     \
        : "v"((A)[0]), "v"((A)[1]), "v"((A)[2]), "v"((A)[3]),           \
          "v"((A)[4]), "v"((A)[5]), "v"((A)[6]), "v"((A)[7]),           \
          "a"((W)[0]), "a"((W)[1]), "a"((W)[2]), "a"((W)[3]),           \
          "a"((W)[4]), "a"((W)[5]), "a"((W)[6]), "a"((W)[7]))

__global__ __launch_bounds__(NT, 2) void rnn_kernel(
    const float* __restrict__ x,      // [B, T]
    const float* __restrict__ W_ih,   // [H, 1]
    const float* __restrict__ W_hh,   // [H, H]
    const float* __restrict__ b_ih,   // [H]
    const float* __restrict__ b_hh,   // [H]
    const float* __restrict__ W_out,  // [1, H]
    const float* __restrict__ b_out,  // [1]
    float* __restrict__ out)          // [B, T+FUT]
{
    __shared__ __align__(16) uint32_t hbuf[2][SPB * HID];   // packed (hi|lo), swizzled
    __shared__ __align__(16) float xstg[128][8];            // x chunk (cols 0..3 used)
    __shared__ __align__(16) float outbuf[2][SPB][68];      // o ring, padded
    __shared__ __align__(16) float opart[2][16];            // o partials [r*4+wid]

    const int tid  = threadIdx.x;
    const int lane = tid & 63;
    const int wid  = tid >> 6;        // wave w: owns cols 32w..32w+31
    const int l15  = lane & 15;
    const int g    = lane >> 4;       // lane quarter
    const int s0   = blockIdx.x * SPB;

    // ---- weight fragments (packed hi|lo), homed in 128 AGPRs ----
    // Slot map (A and B identical): G, slot s=8g+e -> real k=16G+4g+(e>>1),
    // parity e&1 selects hi/lo. W1 u32 = hi|lo<<16, W2 = lo|hi<<16.
    const int j0 = wid * 32 + l15;
    const int j1 = j0 + 16;
    u32x4 W1a[8], W2a[8], W1b[8], W2b[8];
    {
        const float* r0 = W_hh + (size_t)j0 * HID;
        const float* r1 = W_hh + (size_t)j1 * HID;
        #pragma unroll
        for (int G = 0; G < 8; ++G) {
            const int kb = G * 16 + g * 4;
            #pragma unroll
            for (int t = 0; t < 4; ++t) {
                const float wa = r0[kb + t];
                const float wb = r1[kb + t];
                const uint32_t ha = bf16_rn(wa);
                const uint32_t la = bf16_rn(wa - bf16f((unsigned short)ha));
                const uint32_t hb_ = bf16_rn(wb);
                const uint32_t lb = bf16_rn(wb - bf16f((unsigned short)hb_));
                W1a[G][t] = ha | (la << 16);
                W2a[G][t] = la | (ha << 16);
                W1b[G][t] = hb_ | (lb << 16);
                W2b[G][t] = lb | (hb_ << 16);
            }
        }
    }
    const float bias0 = b_ih[j0] + b_hh[j0];
    const float bias1 = b_ih[j1] + b_hh[j1];
    const float wih0  = W_ih[j0], wih1 = W_ih[j1];
    const float wout0 = W_out[j0], wout1 = W_out[j1];
    const float bo    = b_out[0];

    // ---- LDS byte offsets; swizzle byte ^= (row&3)<<4 (rows 0..3 used) ----
    const int abase = l15 * 512 + ((g * 16) ^ ((l15 & 3) << 4));
    int woffA[4], woffB[4];
    #pragma unroll
    for (int r = 0; r < 4; ++r) {      // writes only from g==0 lanes: row=r
        const int swz = (r & 3) << 4;
        woffA[r] = r * 512 + ((4 * j0) ^ swz);
        woffB[r] = r * 512 + ((4 * j1) ^ swz);
    }

    for (int idx = tid; idx < 2 * SPB * HID; idx += NT) ((uint32_t*)hbuf)[idx] = 0;
    if (tid < 32) ((float*)opart)[tid] = 0.0f;
    __syncthreads();

    // A-fragments: zero once; exec-masked loads keep l15>=SPB lanes at zero.
    u32x4 A_[8];
    #pragma unroll
    for (int G = 0; G < 8; ++G) A_[G] = (u32x4){0, 0, 0, 0};

    for (int i = 0; i < NSTEP; ++i) {
        const int p = i & 1;

        // refill x chunk every 128 teacher steps
        if (i < TLEN && (i & 127) == 0) {
            #pragma unroll
            for (int pass = 0; pass < 2; ++pass) {
                const int idx = pass * NT + tid;
                const int t = idx & 127, s = idx >> 7;
                xstg[t][s] = x[(size_t)(s0 + s) * TLEN + (i + t)];
            }
            __syncthreads();
        }

        // flush a full 64-entry output ring (o_{i-65}..o_{i-2})
        if (i > 64 && (i & 63) == 1 && tid < 16 * SPB) {
            const int q = ((i - 65) >> 6) & 1;
            const int base = i - 65;
            const int s = tid >> 4, c4 = (tid & 15) * 4;
            const f32x4 v = *(const f32x4*)&outbuf[q][s][c4];
            *(f32x4*)&out[(size_t)(s0 + s) * NSTEP + base + c4] = v;
        }

        // A-fragments (rows >= SPB stay zero via exec mask)
        const char* hbp = (const char*)hbuf[p] + abase;
        if (l15 < SPB) {
            #pragma unroll
            for (int G = 0; G < 8; ++G)
                A_[G] = *(const u32x4*)(hbp + G * 64);
        }

        // finish o_{i-1}: read 16 wave-partials, reduce over waves (DPP)
        float ov = opart[p ^ 1][l15];
        ov += __shfl_xor(ov, 1);
        ov += __shfl_xor(ov, 2);
        const float o = ov + bo;         // lane l15 holds row l15>>2 (garbage at i==0)
        if (i > 0 && wid == 0 && g == 0 && (l15 & 3) == 0)
            outbuf[((i - 1) >> 6) & 1][l15 >> 2][(i - 1) & 63] = o;

        // 32 MFMA in 4 chains; W read from AGPR in place, A/acc in VGPRs
        f32x4 p10 = {0.f,0.f,0.f,0.f}, p11 = p10, p20 = p10, p21 = p10;
        MFMA_CHAIN8(p10, A_, W1a);
        MFMA_CHAIN8(p11, A_, W1b);
        MFMA_CHAIN8(p20, A_, W2a);
        MFMA_CHAIN8(p21, A_, W2b);
        // fence: no VALU read of an MFMA D-reg inside the wait-state window
        asm volatile("s_nop 7\n\ts_nop 7\n\ts_nop 7"
                     : "+v"(p10), "+v"(p11), "+v"(p20), "+v"(p21));

        // per-row inputs (uniform branch)
        float in0, in1, in2, in3;
        if (i < TLEN) {
            const f32x4 xv = *(const f32x4*)&xstg[i & 127][0];
            in0 = xv[0]; in1 = xv[1]; in2 = xv[2]; in3 = xv[3];
        } else {
            in0 = __shfl(o, 0);
            in1 = __shfl(o, 4);
            in2 = __shfl(o, 8);
            in3 = __shfl(o, 12);
        }

        // epilogue: S, tanh, pack (hi|lo), writes from g==0 lanes (rows 0..3)
        char* hw = (char*)hbuf[p ^ 1];
        float opr[4];
        #pragma unroll
        for (int r = 0; r < 4; ++r) {
            const float inr = (r == 0) ? in0 : (r == 1) ? in1 : (r == 2) ? in2 : in3;
            const float S0 = p10[r] + p20[r] + bias0 + inr * wih0;
            const float S1 = p11[r] + p21[r] + bias1 + inr * wih1;
            const float h0 = fast_tanh(S0);
            const float h1 = fast_tanh(S1);
            opr[r] = h0 * wout0 + h1 * wout1;
            uint32_t P;
            asm("v_cvt_pk_bf16_f32 %0, %1, %2" : "=v"(P) : "v"(h0), "v"(h1));
            const float hi0 = __builtin_bit_cast(float, P << 16);
            const float hi1 = __builtin_bit_cast(float, P & 0xffff0000u);
            const float lo0 = h0 - hi0;
            const float lo1 = h1 - hi1;
            uint32_t PL;
            asm("v_cvt_pk_bf16_f32 %0, %1, %2" : "=v"(PL) : "v"(lo0), "v"(lo1));
            if (g == 0) {
                *(uint32_t*)(hw + woffA[r]) = (P & 0xffffu) | (PL << 16);
                *(uint32_t*)(hw + woffB[r]) = (P >> 16) | (PL & 0xffff0000u);
            }
        }
        // per-wave o-partials: 4-stage DPP tree within the 16-lane group
        #pragma unroll
        for (int r = 0; r < 4; ++r) {
            opr[r] += __shfl_xor(opr[r], 1);
            opr[r] += __shfl_xor(opr[r], 2);
            opr[r] += __shfl_xor(opr[r], 4);
            opr[r] += __shfl_xor(opr[r], 8);
        }
        if (lane == 0) {
            #pragma unroll
            for (int r = 0; r < 4; ++r) opart[p][r * 4 + wid] = opr[r];
        }
        __syncthreads();   // the one per-step barrier
    }

    // tail: finish o_{NSTEP-1} (partials in opart[(NSTEP-1)&1]), flush ring
    {
        float ov = opart[(NSTEP - 1) & 1][l15];
        ov += __shfl_xor(ov, 1);
        ov += __shfl_xor(ov, 2);
        const float o = ov + bo;
        if (wid == 0 && g == 0 && (l15 & 3) == 0)
            outbuf[((NSTEP - 1) >> 6) & 1][l15 >> 2][(NSTEP - 1) & 63] = o;
    }
    __syncthreads();
    if (tid < 16 * SPB) {   // flush t = 1024..1087
        const int s = tid >> 4, c4 = (tid & 15) * 4;
        const f32x4 v = *(const f32x4*)&outbuf[0][s][c4];
        *(f32x4*)&out[(size_t)(s0 + s) * NSTEP + TLEN + c4] = v;
    }
}

extern "C" void kernel_launch(void* const* d_in, const int* in_sizes, int n_in,
                              void* d_out, int out_size, void* d_ws, size_t ws_size,
                              hipStream_t stream) {
    const float* x     = (const float*)d_in[0];
    const float* W_ih  = (const float*)d_in[1];
    const float* W_hh  = (const float*)d_in[2];
    const float* b_ih  = (const float*)d_in[3];
    const float* b_hh  = (const float*)d_in[4];
    const float* W_out = (const float*)d_in[5];
    const float* b_out = (const float*)d_in[6];
    float* out = (float*)d_out;

    dim3 grid(2048 / SPB);   // 512 blocks -> 2 per CU
    dim3 block(NT);
    rnn_kernel<<<grid, block, 0, stream>>>(x, W_ih, W_hh, b_ih, b_hh,
                                           W_out, b_out, out);
}

// Round 10
// 821.855 us; speedup vs baseline: 2.0055x; 2.0055x over previous
//
#include <hip/hip_runtime.h>
#include <stdint.h>
#include <math.h>

// RNN predictor: B=2048, T=1024 teacher + FUT=64 AR, H=128.
// Round-10: minimal-issue step. Insight: VALUBusy includes MFMA, so the real
// budget is MFMA-issue-dominated. Changes vs R8/R9:
//  - UNPACKED hi/lo 3-product (R3 numerics): 24 MFMA/wave-step, full K=32
//    per MFMA, 64 weight VGPRs (vs packed: 40 MFMA, 128 VGPRs).
//  - samples live at A-rows {0,4,8,12} -> each sample's C-row is reg 0 of
//    lane-group g==sample -> epilogue = ONE row per lane (2 tanh), no selects.
//  - o = Wout.h: 2 fma + 4-stage shfl_xor + 1 opart write; finished next
//    step with 1 read + 2 shfl. No o-MFMA chain.
//  - separate hi/lo h-buffers, XOR swizzle (row&1)<<6: reads and writes are
//    exactly 2-way bank aliased (free per m136).
//  - ~165 VGPR under __launch_bounds__(256,2): no pressure, builtin MFMA,
//    2 anti-phase blocks/CU.

#define TLEN  1024
#define FUT   64
#define HID   128
#define SPB   4
#define NT    256
#define NSTEP (TLEN + FUT)

typedef float f32x4 __attribute__((ext_vector_type(4)));
typedef short bf16x8 __attribute__((ext_vector_type(8)));

__device__ __forceinline__ float fast_tanh(float v) {
    return 1.0f - 2.0f / (__expf(2.0f * v) + 1.0f);   // saturates correctly
}
__device__ __forceinline__ unsigned short bf16_rn(float f) {
    uint32_t u = __builtin_bit_cast(uint32_t, f);
    uint32_t r = (u + 0x7fffu + ((u >> 16) & 1u)) >> 16;  // RNE
    return (unsigned short)r;
}
__device__ __forceinline__ float bf16f(unsigned short h) {
    uint32_t u = (uint32_t)h << 16;
    return __builtin_bit_cast(float, u);
}

__global__ __launch_bounds__(NT, 2) void rnn_kernel(
    const float* __restrict__ x,      // [B, T]
    const float* __restrict__ W_ih,   // [H, 1]
    const float* __restrict__ W_hh,   // [H, H]
    const float* __restrict__ b_ih,   // [H]
    const float* __restrict__ b_hh,   // [H]
    const float* __restrict__ W_out,  // [1, H]
    const float* __restrict__ b_out,  // [1]
    float* __restrict__ out)          // [B, T+FUT]
{
    // h: [p][hi/lo][row 0..3][col 0..127] u16; byte ^= (row&1)<<6
    __shared__ __align__(16) unsigned short lds_h[2 * 2 * SPB * HID];
    __shared__ __align__(16) float xstg[128][8];        // [t][sample] (0..3 used)
    __shared__ __align__(16) float outbuf[2][SPB][68];  // o ring, padded
    __shared__ __align__(16) float opart[2][16];        // [sample*4 + wave]

    const int tid  = threadIdx.x;
    const int lane = tid & 63;
    const int wid  = tid >> 6;        // wave w: cols 32w..32w+31
    const int l15  = lane & 15;
    const int g    = lane >> 4;       // lane-group = SAMPLE index in epilogue
    const int s0   = blockIdx.x * SPB;

    // ---- weight B-fragments, 64 VGPRs: lane (g,l15) col j, k=kt*32+8g+e ----
    const int j0 = wid * 32 + l15;
    const int j1 = j0 + 16;
    bf16x8 WhiA[4], WloA[4], WhiB[4], WloB[4];
    {
        const float* r0 = W_hh + (size_t)j0 * HID;
        const float* r1 = W_hh + (size_t)j1 * HID;
        #pragma unroll
        for (int kt = 0; kt < 4; ++kt) {
            const int kb = kt * 32 + g * 8;
            #pragma unroll
            for (int e = 0; e < 8; ++e) {
                const float wa = r0[kb + e];
                const unsigned short ha = bf16_rn(wa);
                WhiA[kt][e] = (short)ha;
                WloA[kt][e] = (short)bf16_rn(wa - bf16f(ha));
                const float wb = r1[kb + e];
                const unsigned short hb = bf16_rn(wb);
                WhiB[kt][e] = (short)hb;
                WloB[kt][e] = (short)bf16_rn(wb - bf16f(hb));
            }
        }
    }
    const float bias0 = b_ih[j0] + b_hh[j0];
    const float bias1 = b_ih[j1] + b_hh[j1];
    const float wih0  = W_ih[j0], wih1 = W_ih[j1];
    const float wout0 = W_out[j0], wout1 = W_out[j1];
    const float bo    = b_out[0];

    // ---- LDS byte offsets ----
    // A-read (lanes l15&3==0 only): sample s=l15>>2 at row s; 16B per kt.
    const int s_ = l15 >> 2;
    int aoff[4];
    #pragma unroll
    for (int kt = 0; kt < 4; ++kt)
        aoff[kt] = s_ * 256 + ((kt * 64 + g * 16) ^ ((s_ & 1) << 6));
    // h-write: ALL lanes; sample g, cols j0/j1. lo at +1024, j1 at +32.
    const int woff0 = g * 256 + ((2 * j0) ^ ((g & 1) << 6));

    for (int idx = tid; idx < 2 * 2 * SPB * HID / 2; idx += NT)
        ((uint32_t*)lds_h)[idx] = 0;
    __syncthreads();

    // A-frags zeroed once; exec-masked loads keep inactive lanes at zero.
    bf16x8 ahi[4], alo[4];
    #pragma unroll
    for (int kt = 0; kt < 4; ++kt) {
        ahi[kt] = (bf16x8){0,0,0,0,0,0,0,0};
        alo[kt] = (bf16x8){0,0,0,0,0,0,0,0};
    }

    for (int i = 0; i < NSTEP; ++i) {
        const int p = i & 1;

        // refill x chunk every 128 teacher steps (coalesced along t)
        if (i < TLEN && (i & 127) == 0) {
            #pragma unroll
            for (int pass = 0; pass < 2; ++pass) {
                const int idx = pass * NT + tid;
                const int t = idx & 127, s = idx >> 7;
                xstg[t][s] = x[(size_t)(s0 + s) * TLEN + (i + t)];
            }
            __syncthreads();
        }

        // flush a full 64-entry output ring (o_{i-65}..o_{i-2})
        if (i > 64 && (i & 63) == 1 && tid < 16 * SPB) {
            const int q = ((i - 65) >> 6) & 1;
            const int s = tid >> 4, c4 = (tid & 15) * 4;
            const f32x4 v = *(const f32x4*)&outbuf[q][s][c4];
            *(f32x4*)&out[(size_t)(s0 + s) * NSTEP + (i - 65) + c4] = v;
        }

        // A-fragments of h(t) (only l15&3==0 lanes load; rest stay zero)
        const char* hb = (const char*)lds_h + p * 2048;
        if ((l15 & 3) == 0) {
            #pragma unroll
            for (int kt = 0; kt < 4; ++kt) {
                ahi[kt] = *(const bf16x8*)(hb + aoff[kt]);
                alo[kt] = *(const bf16x8*)(hb + aoff[kt] + 1024);
            }
        }

        // finish o_{i-1}: lane l15 reads slot l15 = sample(l15>>2), wave(l15&3)
        float ov = opart[p ^ 1][l15];
        ov += __shfl_xor(ov, 1);
        ov += __shfl_xor(ov, 2);
        const float o = ov + bo;        // lanes 4s.. hold o(sample s); junk at i==0
        if (i > 0 && wid == 0 && g == 0 && (l15 & 3) == 0)
            outbuf[((i - 1) >> 6) & 1][l15 >> 2][(i - 1) & 63] = o;

        // 24 MFMA in 6 independent chains (full K=32 each)
        f32x4 p1a = {0.f,0.f,0.f,0.f}, p2a = p1a, p3a = p1a;
        f32x4 p1b = p1a, p2b = p1a, p3b = p1a;
        #pragma unroll
        for (int kt = 0; kt < 4; ++kt) {
            p1a = __builtin_amdgcn_mfma_f32_16x16x32_bf16(ahi[kt], WhiA[kt], p1a, 0, 0, 0);
            p1b = __builtin_amdgcn_mfma_f32_16x16x32_bf16(ahi[kt], WhiB[kt], p1b, 0, 0, 0);
            p2a = __builtin_amdgcn_mfma_f32_16x16x32_bf16(alo[kt], WhiA[kt], p2a, 0, 0, 0);
            p2b = __builtin_amdgcn_mfma_f32_16x16x32_bf16(alo[kt], WhiB[kt], p2b, 0, 0, 0);
            p3a = __builtin_amdgcn_mfma_f32_16x16x32_bf16(ahi[kt], WloA[kt], p3a, 0, 0, 0);
            p3b = __builtin_amdgcn_mfma_f32_16x16x32_bf16(ahi[kt], WloB[kt], p3b, 0, 0, 0);
        }

        // per-lane input for sample g (uniform branch)
        float in;
        if (i < TLEN) in = xstg[i & 127][g];
        else          in = __shfl(o, g << 2);

        // epilogue: ONE row per lane (sample g, cols j0/j1)
        const float S0 = p1a[0] + p2a[0] + p3a[0] + bias0 + in * wih0;
        const float S1 = p1b[0] + p2b[0] + p3b[0] + bias1 + in * wih1;
        const float h0 = fast_tanh(S0);
        const float h1 = fast_tanh(S1);

        char* hw = (char*)lds_h + (p ^ 1) * 2048;
        uint32_t P;
        asm("v_cvt_pk_bf16_f32 %0, %1, %2" : "=v"(P) : "v"(h0), "v"(h1));
        const float rhi0 = __builtin_bit_cast(float, P << 16);
        const float rhi1 = __builtin_bit_cast(float, P & 0xffff0000u);
        uint32_t PL;
        asm("v_cvt_pk_bf16_f32 %0, %1, %2" : "=v"(PL) : "v"(h0 - rhi0), "v"(h1 - rhi1));
        *(unsigned short*)(hw + woff0)        = (unsigned short)P;          // hi0
        *(unsigned short*)(hw + woff0 + 32)   = (unsigned short)(P >> 16);  // hi1
        *(unsigned short*)(hw + woff0 + 1024) = (unsigned short)PL;         // lo0
        *(unsigned short*)(hw + woff0 + 1056) = (unsigned short)(PL >> 16); // lo1

        // o-partials: reduce this wave's 32 cols for sample g
        float op = h0 * wout0 + h1 * wout1;
        op += __shfl_xor(op, 1);
        op += __shfl_xor(op, 2);
        op += __shfl_xor(op, 4);
        op += __shfl_xor(op, 8);
        if (l15 == 0) opart[p][g * 4 + wid] = op;

        __syncthreads();   // the one per-step barrier
    }

    // tail: finish o_{NSTEP-1}, flush last 64 outputs
    {
        float ov = opart[(NSTEP - 1) & 1][l15];
        ov += __shfl_xor(ov, 1);
        ov += __shfl_xor(ov, 2);
        const float o = ov + bo;
        if (wid == 0 && g == 0 && (l15 & 3) == 0)
            outbuf[((NSTEP - 1) >> 6) & 1][l15 >> 2][(NSTEP - 1) & 63] = o;
    }
    __syncthreads();
    if (tid < 16 * SPB) {   // flush t = 1024..1087 (ring q = (1024>>6)&1 = 0)
        const int s = tid >> 4, c4 = (tid & 15) * 4;
        const f32x4 v = *(const f32x4*)&outbuf[0][s][c4];
        *(f32x4*)&out[(size_t)(s0 + s) * NSTEP + TLEN + c4] = v;
    }
}

extern "C" void kernel_launch(void* const* d_in, const int* in_sizes, int n_in,
                              void* d_out, int out_size, void* d_ws, size_t ws_size,
                              hipStream_t stream) {
    const float* x     = (const float*)d_in[0];
    const float* W_ih  = (const float*)d_in[1];
    const float* W_hh  = (const float*)d_in[2];
    const float* b_ih  = (const float*)d_in[3];
    const float* b_hh  = (const float*)d_in[4];
    const float* W_out = (const float*)d_in[5];
    const float* b_out = (const float*)d_in[6];
    float* out = (float*)d_out;

    dim3 grid(2048 / SPB);   // 512 blocks -> 2 per CU
    dim3 block(NT);
    rnn_kernel<<<grid, block, 0, stream>>>(x, W_ih, W_hh, b_ih, b_hh,
                                           W_out, b_out, out);
}

// Round 11
// 729.215 us; speedup vs baseline: 2.2603x; 1.1270x over previous
//
#include <hip/hip_runtime.h>
#include <stdint.h>
#include <math.h>

// RNN predictor: B=2048, T=1024 teacher + FUT=64 AR, H=128.
// Round-11: fp16 2-product arithmetic on the R10 structure.
//  - W = Whi + Wlo (both fp16; Wlo stored x4096 to stay normal, rescaled by
//    exact 2^-12 at combine) -> W represented to ~2^-22.
//  - h stored as SINGLE fp16 (RNE): fresh unbiased ~2^-12 rounding per step.
//  - 16 MFMA/wave-step (4 chains: {Whi,Wlo} x 2 col-tiles), mfma_f32_16x16x32_f16.
//  - k-permutation pi(32kt+8g+e) = 16e+4kt+g applied to BOTH A-reads and
//    B-register loads (contraction invariant): makes cols j0,j1 adjacent in
//    LDS -> ONE ds_write_b32 per lane; 4 ds_read_b128 per wave (half of R10).
//  - row-XOR swizzle (^ row<<5): reads and writes both <=2-way (free, m136).
//  - rest identical to R10 (passed): SPB=4, 512 blocks -> 2/CU anti-phased,
//    one barrier/step, o via per-wave partials + opart rotation, 64-entry
//    output ring flushed as f32x4.

#define TLEN  1024
#define FUT   64
#define HID   128
#define SPB   4
#define NT    256
#define NSTEP (TLEN + FUT)

typedef float f32x4 __attribute__((ext_vector_type(4)));
typedef _Float16 f16x8 __attribute__((ext_vector_type(8)));
typedef uint32_t u32x4 __attribute__((ext_vector_type(4)));

__device__ __forceinline__ f16x8 asf16(u32x4 v) {
    return __builtin_bit_cast(f16x8, v);
}
__device__ __forceinline__ float fast_tanh(float v) {
    return 1.0f - 2.0f / (__expf(2.0f * v) + 1.0f);   // saturates correctly
}

__global__ __launch_bounds__(NT, 2) void rnn_kernel(
    const float* __restrict__ x,      // [B, T]
    const float* __restrict__ W_ih,   // [H, 1]
    const float* __restrict__ W_hh,   // [H, H]
    const float* __restrict__ b_ih,   // [H]
    const float* __restrict__ b_hh,   // [H]
    const float* __restrict__ W_out,  // [1, H]
    const float* __restrict__ b_out,  // [1]
    float* __restrict__ out)          // [B, T+FUT]
{
    // h: [p][row s<4][pos] fp16, pos(c) = (c&15)*8 + (c>>4), byte ^= (s<<5)
    __shared__ __align__(16) unsigned short lds_h[2][SPB * HID];
    __shared__ __align__(16) float xstg[128][8];        // [t][sample] (0..3 used)
    __shared__ __align__(16) float outbuf[2][SPB][68];  // o ring, padded
    __shared__ __align__(16) float opart[2][16];        // [sample*4 + wave]

    const int tid  = threadIdx.x;
    const int lane = tid & 63;
    const int wid  = tid >> 6;        // wave w: cols 32w..32w+31
    const int l15  = lane & 15;
    const int g    = lane >> 4;       // lane-group = sample index in epilogue
    const int s0   = blockIdx.x * SPB;

    // ---- weight B-fragments (fp16 hi/lo), 64 VGPRs ----
    // B slot (kt, gB=g, e) -> k = 16e + 4kt + g (the pi permutation).
    const int j0 = wid * 32 + l15;
    const int j1 = j0 + 16;
    f16x8 WhiA[4], WloA[4], WhiB[4], WloB[4];
    {
        const float* r0 = W_hh + (size_t)j0 * HID;
        const float* r1 = W_hh + (size_t)j1 * HID;
        #pragma unroll
        for (int kt = 0; kt < 4; ++kt) {
            #pragma unroll
            for (int e = 0; e < 8; ++e) {
                const int k = 16 * e + 4 * kt + g;
                const float wa = r0[k];
                const _Float16 wha = (_Float16)wa;
                WhiA[kt][e] = wha;
                WloA[kt][e] = (_Float16)((wa - (float)wha) * 4096.0f);
                const float wb = r1[k];
                const _Float16 whb = (_Float16)wb;
                WhiB[kt][e] = whb;
                WloB[kt][e] = (_Float16)((wb - (float)whb) * 4096.0f);
            }
        }
    }
    const float bias0 = b_ih[j0] + b_hh[j0];
    const float bias1 = b_ih[j1] + b_hh[j1];
    const float wih0  = W_ih[j0], wih1 = W_ih[j1];
    const float wout0 = W_out[j0], wout1 = W_out[j1];
    const float bo    = b_out[0];
    const float CLO   = 1.0f / 4096.0f;   // exact pow2 rescale of the lo product

    // ---- LDS byte offsets ----
    // A-read (lanes l15&3==0): sample s_=l15>>2 at row s_; 16B per kt.
    const int s_ = l15 >> 2;
    int aoff[4];
    #pragma unroll
    for (int kt = 0; kt < 4; ++kt)
        aoff[kt] = s_ * 256 + (((4 * kt + g) * 16) ^ (s_ << 5));
    // h-write: ALL lanes; sample g, packed (j0,j1) fp16 pair -> one b32.
    const int woff = g * 256 + ((l15 * 16 + wid * 4) ^ (g << 5));

    for (int idx = tid; idx < 2 * SPB * HID / 2; idx += NT)
        ((uint32_t*)lds_h)[idx] = 0;
    __syncthreads();

    // A-frags zeroed once; exec-masked loads keep inactive lanes at zero.
    u32x4 A_[4];
    #pragma unroll
    for (int kt = 0; kt < 4; ++kt) A_[kt] = (u32x4){0, 0, 0, 0};

    for (int i = 0; i < NSTEP; ++i) {
        const int p = i & 1;

        // refill x chunk every 128 teacher steps (coalesced along t)
        if (i < TLEN && (i & 127) == 0) {
            #pragma unroll
            for (int pass = 0; pass < 2; ++pass) {
                const int idx = pass * NT + tid;
                const int t = idx & 127, s = idx >> 7;
                xstg[t][s] = x[(size_t)(s0 + s) * TLEN + (i + t)];
            }
            __syncthreads();
        }

        // flush a full 64-entry output ring (o_{i-65}..o_{i-2})
        if (i > 64 && (i & 63) == 1 && tid < 16 * SPB) {
            const int q = ((i - 65) >> 6) & 1;
            const int s = tid >> 4, c4 = (tid & 15) * 4;
            const f32x4 v = *(const f32x4*)&outbuf[q][s][c4];
            *(f32x4*)&out[(size_t)(s0 + s) * NSTEP + (i - 65) + c4] = v;
        }

        // A-fragments of h(t) (only l15&3==0 lanes load; rest stay zero)
        const char* hb = (const char*)lds_h[p];
        if ((l15 & 3) == 0) {
            #pragma unroll
            for (int kt = 0; kt < 4; ++kt)
                A_[kt] = *(const u32x4*)(hb + aoff[kt]);
        }

        // finish o_{i-1}: lane l15 reads slot l15 = sample(l15>>2), wave(l15&3)
        float ov = opart[p ^ 1][l15];
        ov += __shfl_xor(ov, 1);
        ov += __shfl_xor(ov, 2);
        const float o = ov + bo;        // quad q holds o(sample q); junk at i==0
        if (i > 0 && wid == 0 && g == 0 && (l15 & 3) == 0)
            outbuf[((i - 1) >> 6) & 1][l15 >> 2][(i - 1) & 63] = o;

        // 16 MFMA in 4 independent chains (full K=32 each)
        f32x4 pha = {0.f,0.f,0.f,0.f}, phb = pha, pla = pha, plb = pha;
        #pragma unroll
        for (int kt = 0; kt < 4; ++kt) {
            pha = __builtin_amdgcn_mfma_f32_16x16x32_f16(asf16(A_[kt]), WhiA[kt], pha, 0, 0, 0);
            phb = __builtin_amdgcn_mfma_f32_16x16x32_f16(asf16(A_[kt]), WhiB[kt], phb, 0, 0, 0);
            pla = __builtin_amdgcn_mfma_f32_16x16x32_f16(asf16(A_[kt]), WloA[kt], pla, 0, 0, 0);
            plb = __builtin_amdgcn_mfma_f32_16x16x32_f16(asf16(A_[kt]), WloB[kt], plb, 0, 0, 0);
        }

        // per-lane input for sample g (uniform branch)
        float in;
        if (i < TLEN) in = xstg[i & 127][g];
        else          in = __shfl(o, g << 2);

        // epilogue: ONE row per lane (sample g, cols j0/j1)
        const float S0 = fmaf(CLO, pla[0], pha[0]) + bias0 + in * wih0;
        const float S1 = fmaf(CLO, plb[0], phb[0]) + bias1 + in * wih1;
        const float h0 = fast_tanh(S0);
        const float h1 = fast_tanh(S1);

        // pack (fp16(h0), fp16(h1)) -> one b32 write
        const _Float16 q0 = (_Float16)h0;          // RNE
        const _Float16 q1 = (_Float16)h1;
        const uint32_t pv = (uint32_t)__builtin_bit_cast(unsigned short, q0)
                          | ((uint32_t)__builtin_bit_cast(unsigned short, q1) << 16);
        *(uint32_t*)((char*)lds_h[p ^ 1] + woff) = pv;

        // o-partials: reduce this wave's 32 cols for sample g
        float op = h0 * wout0 + h1 * wout1;
        op += __shfl_xor(op, 1);
        op += __shfl_xor(op, 2);
        op += __shfl_xor(op, 4);
        op += __shfl_xor(op, 8);
        if (l15 == 0) opart[p][g * 4 + wid] = op;

        __syncthreads();   // the one per-step barrier
    }

    // tail: finish o_{NSTEP-1}, flush last 64 outputs
    {
        float ov = opart[(NSTEP - 1) & 1][l15];
        ov += __shfl_xor(ov, 1);
        ov += __shfl_xor(ov, 2);
        const float o = ov + bo;
        if (wid == 0 && g == 0 && (l15 & 3) == 0)
            outbuf[((NSTEP - 1) >> 6) & 1][l15 >> 2][(NSTEP - 1) & 63] = o;
    }
    __syncthreads();
    if (tid < 16 * SPB) {   // flush t = 1024..1087 (ring q = 0)
        const int s = tid >> 4, c4 = (tid & 15) * 4;
        const f32x4 v = *(const f32x4*)&outbuf[0][s][c4];
        *(f32x4*)&out[(size_t)(s0 + s) * NSTEP + TLEN + c4] = v;
    }
}

extern "C" void kernel_launch(void* const* d_in, const int* in_sizes, int n_in,
                              void* d_out, int out_size, void* d_ws, size_t ws_size,
                              hipStream_t stream) {
    const float* x     = (const float*)d_in[0];
    const float* W_ih  = (const float*)d_in[1];
    const float* W_hh  = (const float*)d_in[2];
    const float* b_ih  = (const float*)d_in[3];
    const float* b_hh  = (const float*)d_in[4];
    const float* W_out = (const float*)d_in[5];
    const float* b_out = (const float*)d_in[6];
    float* out = (float*)d_out;

    dim3 grid(2048 / SPB);   // 512 blocks -> 2 per CU
    dim3 block(NT);
    rnn_kernel<<<grid, block, 0, stream>>>(x, W_ih, W_hh, b_ih, b_hh,
                                           W_out, b_out, out);
}